// Round 21
// baseline (108.580 us; speedup 1.0000x reference)
//
#include <hip/hip_runtime.h>
#include <math.h>

#define S      4096
#define BEV    16
#define KNN    5
#define BIGF   1.0e9f
#define NSL    32           // slices per candidate scan
#define GPP    8            // query-pairs per knn block
#define NTH    256          // = GPP * NSL
#define RSTR   81           // per-slice LDS row stride in elements (GPP*10 + 1 pad)

__device__ __forceinline__ float fmulrn(float a, float b) { return __fmul_rn(a, b); }
__device__ __forceinline__ float faddrn(float a, float b) { return __fadd_rn(a, b); }

// ---- K1: per-(event,chunk) stats: chunk max score, query/cand counts (no atomics) ----
__global__ __launch_bounds__(1024) void k_scan(const float* __restrict__ score,
                                               float* __restrict__ mrss4,
                                               int* __restrict__ qn, int* __restrict__ cn) {
    int blk = blockIdx.x, t = threadIdx.x;
    int b = blk >> 2, ch = blk & 3;
    float v = score[(size_t)b * S + ch * 1024 + t];
    float m = v;
    int pk = (v > 0.5f) ? (1 << 16) : 1;
#pragma unroll
    for (int off = 32; off >= 1; off >>= 1) {
        m = fmaxf(m, __shfl_xor(m, off, 64));
        pk += __shfl_xor(pk, off, 64);
    }
    __shared__ float wm[16];
    __shared__ int wp[16];
    int wid = t >> 6;
    if ((t & 63) == 0) { wm[wid] = m; wp[wid] = pk; }
    __syncthreads();
    if (t == 0) {
        float mm = wm[0]; int pp = wp[0];
        for (int w = 1; w < 16; w++) { mm = fmaxf(mm, wm[w]); pp += wp[w]; }
        mrss4[blk] = mm;
        qn[blk] = pp & 0xffff;
        cn[blk] = pp >> 16;
    }
}

// ---- K2: threshold + prefix offsets (single thread; tiny) ----
__global__ void k_off(const float* __restrict__ mrss4,
                      const int* __restrict__ qn, const int* __restrict__ cn,
                      float* __restrict__ thrv,
                      int* __restrict__ qchoff, int* __restrict__ cchoff,
                      int* __restrict__ qcount, int* __restrict__ ccount,
                      int* __restrict__ qpoff) {
    if (threadIdx.x != 0) return;
    float mn = 3.0e38f;
    for (int b = 0; b < BEV; b++) {
        float mx = mrss4[b * 4];
        for (int ch = 1; ch < 4; ch++) mx = fmaxf(mx, mrss4[b * 4 + ch]);
        mn = fminf(mn, mx);
    }
    // rn(0.98*x) monotone => min of products == product of min; clamp 0.5
    thrv[0] = fminf(__fmul_rn(mn, 0.98f), 0.5f);
    int qp = 0;
    for (int b = 0; b < BEV; b++) {
        int qq = 0, cc = 0;
        for (int ch = 0; ch < 4; ch++) {
            qchoff[b * 4 + ch] = qq; cchoff[b * 4 + ch] = cc;
            qq += qn[b * 4 + ch];    cc += cn[b * 4 + ch];
        }
        qcount[b] = qq; ccount[b] = cc;
        qpoff[b] = qp; qp += (qq + 1) >> 1;      // pairs of query rows
    }
    qpoff[BEV] = qp;
}

// ---- K3: ordered compaction + sel_mask + candidate defaults + sel counts ----
__global__ __launch_bounds__(1024) void k_sel(const float* __restrict__ score,
                                              const float* __restrict__ coords,
                                              const float* __restrict__ thrv,
                                              const int* __restrict__ qchoff,
                                              const int* __restrict__ cchoff,
                                              int* __restrict__ scount,
                                              int* __restrict__ qlist,
                                              int* __restrict__ clist,
                                              float4* __restrict__ qpts,
                                              float4* __restrict__ ptsc,
                                              float* __restrict__ out_nidx,
                                              float* __restrict__ out_dist,
                                              float* __restrict__ out_w,
                                              float* __restrict__ out_sel) {
    int blk = blockIdx.x, t = threadIdx.x;
    int b = blk >> 2, ch = blk & 3;
    int p = ch * 1024 + t;
    size_t gi = (size_t)b * S + p;
    float v = score[gi];
    float thr = thrv[0];
    out_sel[gi] = (v >= thr) ? 1.0f : 0.0f;
    bool cand = (v > 0.5f);
    int pk = cand ? (1 << 16) : 1;
    int incl = pk;
#pragma unroll
    for (int off = 1; off < 64; off <<= 1) {
        int u = __shfl_up(incl, off, 64);
        if ((t & 63) >= off) incl += u;
    }
    __shared__ int wtot[16];
    __shared__ int wsel[16];
    int wid = t >> 6;
    if ((t & 63) == 63) wtot[wid] = incl;
    int sel = (v >= thr) ? 1 : 0;
#pragma unroll
    for (int off = 32; off >= 1; off >>= 1) sel += __shfl_xor(sel, off, 64);
    if ((t & 63) == 0) wsel[wid] = sel;
    __syncthreads();
    int base = 0;
    for (int w = 0; w < wid; w++) base += wtot[w];
    int excl = base + incl - pk;
    if (t == 0) {
        int sc2 = 0;
        for (int w = 0; w < 16; w++) sc2 += wsel[w];
        scount[blk] = sc2;
    }
    const float* c = coords + gi * 3;
    float x = c[0], y = c[1], z = c[2];
    float xx = faddrn(faddrn(fmulrn(x, x), fmulrn(y, y)), fmulrn(z, z));
    size_t ebase = (size_t)b * S;
    if (cand) {
        int pos = cchoff[blk] + (excl >> 16);
        clist[ebase + pos] = p;
        ptsc[ebase + pos] = make_float4(fmulrn(-2.0f, x), fmulrn(-2.0f, y),
                                        fmulrn(-2.0f, z), xx);
        // direction-0 rows: fixed default outputs
#pragma unroll
        for (int k = 0; k < KNN; k++) {
            out_nidx[gi * KNN + k] = -1.0f;
            out_dist[gi * KNN + k] = 0.0f;
            out_w[gi * KNN + k]    = 0.2f;
        }
    } else {
        int pos = qchoff[blk] + (excl & 0xffff);
        qlist[ebase + pos] = p;
        qpts[ebase + pos] = make_float4(x, y, z, xx);
    }
}

// strict-< sorted insert of one key into a 5-ladder of unique u64 keys (static idx)
#define INSK(KA, key) { \
    if (key < KA##4) { \
        KA##4 = key; \
        if (KA##4 < KA##3) { unsigned long long u_ = KA##3; KA##3 = KA##4; KA##4 = u_; } \
        if (KA##3 < KA##2) { unsigned long long u_ = KA##2; KA##2 = KA##3; KA##3 = u_; } \
        if (KA##2 < KA##1) { unsigned long long u_ = KA##1; KA##1 = KA##2; KA##2 = u_; } \
        if (KA##1 < KA##0) { unsigned long long u_ = KA##0; KA##0 = KA##1; KA##1 = u_; } \
    } }

// epilogue for one row from a merged 5-ladder (static names)
#define EPILOG(KA, rowexpr) { \
    int irow = qlist[ebm + (rowexpr)]; \
    size_t gi = ebm + irow; \
    unsigned long long av[KNN] = { KA##0, KA##1, KA##2, KA##3, KA##4 }; \
    float dk[KNN], nk[KNN], ev[KNN]; \
    float mx_ = -3.0e38f; \
    _Pragma("unroll") \
    for (int k = 0; k < KNN; k++) { \
        float d = __uint_as_float((unsigned int)(av[k] >> 32)); \
        bool val = (d < BIGF); \
        int cpos = (int)(unsigned int)(av[k] & 0xffffffffu); \
        if (!val || cpos >= S || cpos < 0) cpos = 0; \
        dk[k] = val ? d : 0.0f; \
        nk[k] = val ? (float)(bm * S + clist[ebm + cpos]) : -1.0f; \
        ev[k] = expf(-dk[k]); \
        mx_ = fmaxf(mx_, ev[k]); \
    } \
    float u_[KNN], ssum_ = 0.0f; \
    _Pragma("unroll") \
    for (int k = 0; k < KNN; k++) { u_[k] = expf(ev[k] - mx_); ssum_ += u_[k]; } \
    _Pragma("unroll") \
    for (int k = 0; k < KNN; k++) { \
        out_nidx[gi * KNN + k] = nk[k]; \
        out_dist[gi * KNN + k] = dk[k]; \
        out_w[gi * KNN + k]    = u_[k] / ssum_; \
    } }

// ---- K4: fused KNN: r10 scan + parallel butterfly merge ----
__global__ __launch_bounds__(NTH, 4) void k_knn(const float4* __restrict__ ptsc,
                                                const float4* __restrict__ qpts,
                                                const int* __restrict__ qlist,
                                                const int* __restrict__ clist,
                                                const int* __restrict__ qpoff,
                                                const int* __restrict__ qcount,
                                                const int* __restrict__ ccount,
                                                const int* __restrict__ scount,
                                                float* __restrict__ out_nidx,
                                                float* __restrict__ out_dist,
                                                float* __restrict__ out_w,
                                                float* __restrict__ out_rsup) {
    int pg = blockIdx.x, t = threadIdx.x;
    if (pg == 0 && t == 0) {                     // rs_up prefix (17 floats)
        int acc = 0;
        out_rsup[0] = 0.0f;
        for (int e = 0; e < BEV; e++) {
            acc += scount[e * 4] + scount[e * 4 + 1] + scount[e * 4 + 2] + scount[e * 4 + 3];
            out_rsup[e + 1] = (float)acc;
        }
    }
    int total = qpoff[BEV];
    if (pg * GPP >= total) return;               // uniform exit

    __shared__ int sqp[BEV + 1];
    __shared__ int sqc[BEV];
    __shared__ int scc[BEV];
    __shared__ float dpart[NSL * RSTR];          // [sl][pr*10], 10368 B
    __shared__ unsigned short ipart[NSL * RSTR]; // 5184 B
    if (t < BEV + 1) sqp[t] = qpoff[t];
    if (t < BEV) { sqc[t] = qcount[t]; scc[t] = ccount[t]; }
    __syncthreads();

    // ---------- scan phase (identical to r10) ----------
    int pr = t & (GPP - 1), sl = t >> 3;         // 8 pairs x 32 slices
    int gpr = pg * GPP + pr;
    bool pact = gpr < total;
    int gp = pact ? gpr : (total - 1);
    int b = 0;
#pragma unroll
    for (int e = 1; e < BEV; e++) b += (gp >= sqp[e]) ? 1 : 0;
    int rp = gp - sqp[b];
    int qc = sqc[b], cc = scc[b];
    int r0 = 2 * rp, r1 = r0 + 1;
    bool a1v = pact && (r1 < qc);
    size_t ebase = (size_t)b * S;
    float4 q0 = qpts[ebase + r0];
    float4 q1 = qpts[ebase + (a1v ? r1 : r0)];

    int slen = (cc + NSL - 1) / NSL;
    int j0 = sl * slen;
    int j1 = min(j0 + slen, cc);

    const float INF = __int_as_float(0x7f800000);
    float A0=INF,A1=INF,A2=INF,A3=INF,A4=INF; int IA0=-1,IA1=-1,IA2=-1,IA3=-1,IA4=-1;
    float B0=INF,B1=INF,B2=INF,B3=INF,B4=INF; int IB0=-1,IB1=-1,IB2=-1,IB3=-1,IB4=-1;
    const float4* __restrict__ pp = ptsc + ebase;

#pragma unroll 4
    for (int j = j0; j < j1; j++) {
        float4 p = pp[j];                        // 8 distinct addrs per wave
        float dm0 = faddrn(faddrn(fmulrn(p.x, q0.x), fmulrn(p.y, q0.y)), fmulrn(p.z, q0.z));
        float dd0 = fmaxf(faddrn(faddrn(q0.w, p.w), dm0), 0.0f);
        float dm1 = faddrn(faddrn(fmulrn(p.x, q1.x), fmulrn(p.y, q1.y)), fmulrn(p.z, q1.z));
        float dd1 = fmaxf(faddrn(faddrn(q1.w, p.w), dm1), 0.0f);
        {   // sorted insert: compares (old values) drive idx; med3 updates values
            bool c0=dd0<A0,c1=dd0<A1,c2=dd0<A2,c3=dd0<A3,c4=dd0<A4;
            IA4=c4?(c3?IA3:j):IA4; IA3=c3?(c2?IA2:j):IA3; IA2=c2?(c1?IA1:j):IA2;
            IA1=c1?(c0?IA0:j):IA1; IA0=c0?j:IA0;
            A4=__builtin_amdgcn_fmed3f(dd0,A3,A4); A3=__builtin_amdgcn_fmed3f(dd0,A2,A3);
            A2=__builtin_amdgcn_fmed3f(dd0,A1,A2); A1=__builtin_amdgcn_fmed3f(dd0,A0,A1);
            A0=fminf(A0,dd0);
        }
        {
            bool c0=dd1<B0,c1=dd1<B1,c2=dd1<B2,c3=dd1<B3,c4=dd1<B4;
            IB4=c4?(c3?IB3:j):IB4; IB3=c3?(c2?IB2:j):IB3; IB2=c2?(c1?IB1:j):IB2;
            IB1=c1?(c0?IB0:j):IB1; IB0=c0?j:IB0;
            B4=__builtin_amdgcn_fmed3f(dd1,B3,B4); B3=__builtin_amdgcn_fmed3f(dd1,B2,B3);
            B2=__builtin_amdgcn_fmed3f(dd1,B1,B2); B1=__builtin_amdgcn_fmed3f(dd1,B0,B1);
            B0=fminf(B0,dd1);
        }
    }

    float* wd = &dpart[sl * RSTR + pr * 10];
    unsigned short* wi = &ipart[sl * RSTR + pr * 10];
    wd[0]=A0; wd[1]=A1; wd[2]=A2; wd[3]=A3; wd[4]=A4;
    wd[5]=B0; wd[6]=B1; wd[7]=B2; wd[8]=B3; wd[9]=B4;
    wi[0]=(unsigned short)(IA0-j0); wi[1]=(unsigned short)(IA1-j0);
    wi[2]=(unsigned short)(IA2-j0); wi[3]=(unsigned short)(IA3-j0);
    wi[4]=(unsigned short)(IA4-j0);
    wi[5]=(unsigned short)(IB0-j0); wi[6]=(unsigned short)(IB1-j0);
    wi[7]=(unsigned short)(IB2-j0); wi[8]=(unsigned short)(IB3-j0);
    wi[9]=(unsigned short)(IB4-j0);
    __syncthreads();

    // ---------- merge phase: group g (32 lanes) = pair g; lane l = slice l ----------
    int g = t >> 5, l = t & 31;
    int gprm = pg * GPP + g;
    bool pactm = gprm < total;
    int gpm = pactm ? gprm : (total - 1);
    int bm = 0;
#pragma unroll
    for (int e = 1; e < BEV; e++) bm += (gpm >= sqp[e]) ? 1 : 0;
    int rpm = gpm - sqp[bm];
    int qcm = sqc[bm], ccm = scc[bm];
    int slenm = (ccm + NSL - 1) / NSL;
    size_t ebm = (size_t)bm * S;

    const float* dpA = &dpart[l * RSTR + g * 10];            // stride 81 dwords: conflict-free
    const unsigned short* ipA = &ipart[l * RSTR + g * 10];
    unsigned long long ka0, ka1, ka2, ka3, ka4, kb0, kb1, kb2, kb3, kb4;
    {
        int base2 = l * slenm;
        ka0 = ((unsigned long long)__float_as_uint(dpA[0]) << 32) | (unsigned int)(base2 + (int)ipA[0]);
        ka1 = ((unsigned long long)__float_as_uint(dpA[1]) << 32) | (unsigned int)(base2 + (int)ipA[1]);
        ka2 = ((unsigned long long)__float_as_uint(dpA[2]) << 32) | (unsigned int)(base2 + (int)ipA[2]);
        ka3 = ((unsigned long long)__float_as_uint(dpA[3]) << 32) | (unsigned int)(base2 + (int)ipA[3]);
        ka4 = ((unsigned long long)__float_as_uint(dpA[4]) << 32) | (unsigned int)(base2 + (int)ipA[4]);
        kb0 = ((unsigned long long)__float_as_uint(dpA[5]) << 32) | (unsigned int)(base2 + (int)ipA[5]);
        kb1 = ((unsigned long long)__float_as_uint(dpA[6]) << 32) | (unsigned int)(base2 + (int)ipA[6]);
        kb2 = ((unsigned long long)__float_as_uint(dpA[7]) << 32) | (unsigned int)(base2 + (int)ipA[7]);
        kb3 = ((unsigned long long)__float_as_uint(dpA[8]) << 32) | (unsigned int)(base2 + (int)ipA[8]);
        kb4 = ((unsigned long long)__float_as_uint(dpA[9]) << 32) | (unsigned int)(base2 + (int)ipA[9]);
    }

    // 5-step butterfly: after step set, every lane holds top-5 of its xor-subgroup.
    // top-5-of-union is merge-order independent (keys unique) -> exact (d, pos) order.
#pragma unroll
    for (int off = 16; off >= 1; off >>= 1) {
        unsigned long long r0k = __shfl_xor(ka0, off, 64);
        unsigned long long r1k = __shfl_xor(ka1, off, 64);
        unsigned long long r2k = __shfl_xor(ka2, off, 64);
        unsigned long long r3k = __shfl_xor(ka3, off, 64);
        unsigned long long r4k = __shfl_xor(ka4, off, 64);
        INSK(ka, r0k) INSK(ka, r1k) INSK(ka, r2k) INSK(ka, r3k) INSK(ka, r4k)
        unsigned long long s0k = __shfl_xor(kb0, off, 64);
        unsigned long long s1k = __shfl_xor(kb1, off, 64);
        unsigned long long s2k = __shfl_xor(kb2, off, 64);
        unsigned long long s3k = __shfl_xor(kb3, off, 64);
        unsigned long long s4k = __shfl_xor(kb4, off, 64);
        INSK(kb, s0k) INSK(kb, s1k) INSK(kb, s2k) INSK(kb, s3k) INSK(kb, s4k)
    }

    if (pactm && l == 0 && 2 * rpm < qcm)       { EPILOG(ka, 2 * rpm) }
    if (pactm && l == 1 && 2 * rpm + 1 < qcm)   { EPILOG(kb, 2 * rpm + 1) }
}

extern "C" void kernel_launch(void* const* d_in, const int* in_sizes, int n_in,
                              void* d_out, int out_size, void* d_ws, size_t ws_size,
                              hipStream_t stream) {
    const float* score  = (const float*)d_in[0];
    const float* coords = (const float*)d_in[1];

    float* out = (float*)d_out;
    size_t NK = (size_t)BEV * S * KNN;
    float* out_nidx = out;
    float* out_dist = out + NK;
    float* out_w    = out + 2 * NK;
    float* out_rsup = out + 3 * NK;
    float* out_sel  = out + 3 * NK + (BEV + 1);

    char* ws = (char*)d_ws;
    float* mrss4  = (float*)(ws + 0);                     // 64 f32
    int* qn       = (int*)(ws + 256);                     // 64
    int* cn       = (int*)(ws + 512);                     // 64
    int* qchoff   = (int*)(ws + 768);                     // 64
    int* cchoff   = (int*)(ws + 1024);                    // 64
    int* qcount   = (int*)(ws + 1280);                    // 16
    int* ccount   = (int*)(ws + 1344);                    // 16
    int* qpoff    = (int*)(ws + 1408);                    // 17
    int* scount   = (int*)(ws + 1536);                    // 64
    float* thrv   = (float*)(ws + 1792);                  // 1
    int* qlist    = (int*)(ws + 2048);                    // BEV*S
    int* clist    = (int*)(ws + 2048 + (size_t)BEV * S * 4);
    float4* qpts  = (float4*)(ws + 2048 + (size_t)BEV * S * 8);      // 16B aligned
    float4* ptsc  = (float4*)(ws + 2048 + (size_t)BEV * S * 8 + (size_t)BEV * S * 16);

    k_scan<<<BEV * 4, 1024, 0, stream>>>(score, mrss4, qn, cn);
    k_off<<<1, 64, 0, stream>>>(mrss4, qn, cn, thrv, qchoff, cchoff,
                                qcount, ccount, qpoff);
    k_sel<<<BEV * 4, 1024, 0, stream>>>(score, coords, thrv, qchoff, cchoff, scount,
                                        qlist, clist, qpts, ptsc,
                                        out_nidx, out_dist, out_w, out_sel);
    k_knn<<<(BEV * ((S + 1) / 2) + GPP - 1) / GPP, NTH, 0, stream>>>(
        ptsc, qpts, qlist, clist, qpoff, qcount, ccount, scount,
        out_nidx, out_dist, out_w, out_rsup);
}

// Round 22
// 84.363 us; speedup vs baseline: 1.2871x; 1.2871x over previous
//
#include <hip/hip_runtime.h>
#include <math.h>

#define S      4096
#define BEV    16
#define KNN    5
#define BIGF   1.0e9f
#define NSL    32           // slices per candidate scan
#define GPP    8            // query-pairs per knn block
#define NTH    256          // = GPP * NSL
#define RSTR   81           // per-slice LDS row stride in elements (GPP*10 + 1 pad)

__device__ __forceinline__ float fmulrn(float a, float b) { return __fmul_rn(a, b); }
__device__ __forceinline__ float faddrn(float a, float b) { return __fadd_rn(a, b); }

// ---- K1: per-(event,chunk) stats: chunk max score, query/cand counts (no atomics) ----
__global__ __launch_bounds__(1024) void k_scan(const float* __restrict__ score,
                                               float* __restrict__ mrss4,
                                               int* __restrict__ qn, int* __restrict__ cn) {
    int blk = blockIdx.x, t = threadIdx.x;
    int b = blk >> 2, ch = blk & 3;
    float v = score[(size_t)b * S + ch * 1024 + t];
    float m = v;
    int pk = (v > 0.5f) ? (1 << 16) : 1;
#pragma unroll
    for (int off = 32; off >= 1; off >>= 1) {
        m = fmaxf(m, __shfl_xor(m, off, 64));
        pk += __shfl_xor(pk, off, 64);
    }
    __shared__ float wm[16];
    __shared__ int wp[16];
    int wid = t >> 6;
    if ((t & 63) == 0) { wm[wid] = m; wp[wid] = pk; }
    __syncthreads();
    if (t == 0) {
        float mm = wm[0]; int pp = wp[0];
        for (int w = 1; w < 16; w++) { mm = fmaxf(mm, wm[w]); pp += wp[w]; }
        mrss4[blk] = mm;
        qn[blk] = pp & 0xffff;
        cn[blk] = pp >> 16;
    }
}

// ---- K2: threshold + prefix offsets (single thread; tiny) ----
__global__ void k_off(const float* __restrict__ mrss4,
                      const int* __restrict__ qn, const int* __restrict__ cn,
                      float* __restrict__ thrv,
                      int* __restrict__ qchoff, int* __restrict__ cchoff,
                      int* __restrict__ qcount, int* __restrict__ ccount,
                      int* __restrict__ qpoff) {
    if (threadIdx.x != 0) return;
    float mn = 3.0e38f;
    for (int b = 0; b < BEV; b++) {
        float mx = mrss4[b * 4];
        for (int ch = 1; ch < 4; ch++) mx = fmaxf(mx, mrss4[b * 4 + ch]);
        mn = fminf(mn, mx);
    }
    // rn(0.98*x) monotone => min of products == product of min; clamp 0.5
    thrv[0] = fminf(__fmul_rn(mn, 0.98f), 0.5f);
    int qp = 0;
    for (int b = 0; b < BEV; b++) {
        int qq = 0, cc = 0;
        for (int ch = 0; ch < 4; ch++) {
            qchoff[b * 4 + ch] = qq; cchoff[b * 4 + ch] = cc;
            qq += qn[b * 4 + ch];    cc += cn[b * 4 + ch];
        }
        qcount[b] = qq; ccount[b] = cc;
        qpoff[b] = qp; qp += (qq + 1) >> 1;      // pairs of query rows
    }
    qpoff[BEV] = qp;
}

// ---- K3: ordered compaction + sel_mask + candidate defaults + sel counts ----
__global__ __launch_bounds__(1024) void k_sel(const float* __restrict__ score,
                                              const float* __restrict__ coords,
                                              const float* __restrict__ thrv,
                                              const int* __restrict__ qchoff,
                                              const int* __restrict__ cchoff,
                                              int* __restrict__ scount,
                                              int* __restrict__ qlist,
                                              int* __restrict__ clist,
                                              float4* __restrict__ qpts,
                                              float4* __restrict__ ptsc,
                                              float* __restrict__ out_nidx,
                                              float* __restrict__ out_dist,
                                              float* __restrict__ out_w,
                                              float* __restrict__ out_sel) {
    int blk = blockIdx.x, t = threadIdx.x;
    int b = blk >> 2, ch = blk & 3;
    int p = ch * 1024 + t;
    size_t gi = (size_t)b * S + p;
    float v = score[gi];
    float thr = thrv[0];
    out_sel[gi] = (v >= thr) ? 1.0f : 0.0f;
    bool cand = (v > 0.5f);
    int pk = cand ? (1 << 16) : 1;
    int incl = pk;
#pragma unroll
    for (int off = 1; off < 64; off <<= 1) {
        int u = __shfl_up(incl, off, 64);
        if ((t & 63) >= off) incl += u;
    }
    __shared__ int wtot[16];
    __shared__ int wsel[16];
    int wid = t >> 6;
    if ((t & 63) == 63) wtot[wid] = incl;
    int sel = (v >= thr) ? 1 : 0;
#pragma unroll
    for (int off = 32; off >= 1; off >>= 1) sel += __shfl_xor(sel, off, 64);
    if ((t & 63) == 0) wsel[wid] = sel;
    __syncthreads();
    int base = 0;
    for (int w = 0; w < wid; w++) base += wtot[w];
    int excl = base + incl - pk;
    if (t == 0) {
        int sc2 = 0;
        for (int w = 0; w < 16; w++) sc2 += wsel[w];
        scount[blk] = sc2;
    }
    const float* c = coords + gi * 3;
    float x = c[0], y = c[1], z = c[2];
    float xx = faddrn(faddrn(fmulrn(x, x), fmulrn(y, y)), fmulrn(z, z));
    size_t ebase = (size_t)b * S;
    if (cand) {
        int pos = cchoff[blk] + (excl >> 16);
        clist[ebase + pos] = p;
        ptsc[ebase + pos] = make_float4(fmulrn(-2.0f, x), fmulrn(-2.0f, y),
                                        fmulrn(-2.0f, z), xx);
        // direction-0 rows: fixed default outputs
#pragma unroll
        for (int k = 0; k < KNN; k++) {
            out_nidx[gi * KNN + k] = -1.0f;
            out_dist[gi * KNN + k] = 0.0f;
            out_w[gi * KNN + k]    = 0.2f;
        }
    } else {
        int pos = qchoff[blk] + (excl & 0xffff);
        qlist[ebase + pos] = p;
        qpts[ebase + pos] = make_float4(x, y, z, xx);
    }
}

// strict-< sorted insert of one unique u64 key into the a0..a4u ladder
#define INS5(key) { \
    if ((key) < a4u) { \
        a4u = (key); \
        if (a4u < a3u) { unsigned long long u_ = a3u; a3u = a4u; a4u = u_; } \
        if (a3u < a2u) { unsigned long long u_ = a2u; a2u = a3u; a3u = u_; } \
        if (a2u < a1u) { unsigned long long u_ = a1u; a1u = a2u; a2u = u_; } \
        if (a1u < a0)  { unsigned long long u_ = a0;  a0  = a1u; a1u = u_; } \
    } }

// ---- K4: fused KNN: r10 scan + 4-way split merge (short serial chain) ----
__global__ __launch_bounds__(NTH, 4) void k_knn(const float4* __restrict__ ptsc,
                                                const float4* __restrict__ qpts,
                                                const int* __restrict__ qlist,
                                                const int* __restrict__ clist,
                                                const int* __restrict__ qpoff,
                                                const int* __restrict__ qcount,
                                                const int* __restrict__ ccount,
                                                const int* __restrict__ scount,
                                                float* __restrict__ out_nidx,
                                                float* __restrict__ out_dist,
                                                float* __restrict__ out_w,
                                                float* __restrict__ out_rsup) {
    int pg = blockIdx.x, t = threadIdx.x;
    if (pg == 0 && t == 0) {                     // rs_up prefix (17 floats)
        int acc = 0;
        out_rsup[0] = 0.0f;
        for (int e = 0; e < BEV; e++) {
            acc += scount[e * 4] + scount[e * 4 + 1] + scount[e * 4 + 2] + scount[e * 4 + 3];
            out_rsup[e + 1] = (float)acc;
        }
    }
    int total = qpoff[BEV];
    if (pg * GPP >= total) return;               // uniform exit

    __shared__ int sqp[BEV + 1];
    __shared__ int sqc[BEV];
    __shared__ int scc[BEV];
    __shared__ float dpart[NSL * RSTR];          // [sl][pr*10], 10368 B
    __shared__ unsigned short ipart[NSL * RSTR]; // 5184 B
    if (t < BEV + 1) sqp[t] = qpoff[t];
    if (t < BEV) { sqc[t] = qcount[t]; scc[t] = ccount[t]; }
    __syncthreads();

    // ---------- scan phase (identical to r10) ----------
    int pr = t & (GPP - 1), sl = t >> 3;         // 8 pairs x 32 slices
    int gpr = pg * GPP + pr;
    bool pact = gpr < total;
    int gp = pact ? gpr : (total - 1);
    int b = 0;
#pragma unroll
    for (int e = 1; e < BEV; e++) b += (gp >= sqp[e]) ? 1 : 0;
    int rp = gp - sqp[b];
    int qc = sqc[b], cc = scc[b];
    int r0 = 2 * rp, r1 = r0 + 1;
    bool a1v = pact && (r1 < qc);
    size_t ebase = (size_t)b * S;
    float4 q0 = qpts[ebase + r0];
    float4 q1 = qpts[ebase + (a1v ? r1 : r0)];

    int slen = (cc + NSL - 1) / NSL;
    int j0 = sl * slen;
    int j1 = min(j0 + slen, cc);

    const float INF = __int_as_float(0x7f800000);
    float A0=INF,A1=INF,A2=INF,A3=INF,A4=INF; int IA0=-1,IA1=-1,IA2=-1,IA3=-1,IA4=-1;
    float B0=INF,B1=INF,B2=INF,B3=INF,B4=INF; int IB0=-1,IB1=-1,IB2=-1,IB3=-1,IB4=-1;
    const float4* __restrict__ pp = ptsc + ebase;

#pragma unroll 4
    for (int j = j0; j < j1; j++) {
        float4 p = pp[j];                        // 8 distinct addrs per wave
        float dm0 = faddrn(faddrn(fmulrn(p.x, q0.x), fmulrn(p.y, q0.y)), fmulrn(p.z, q0.z));
        float dd0 = fmaxf(faddrn(faddrn(q0.w, p.w), dm0), 0.0f);
        float dm1 = faddrn(faddrn(fmulrn(p.x, q1.x), fmulrn(p.y, q1.y)), fmulrn(p.z, q1.z));
        float dd1 = fmaxf(faddrn(faddrn(q1.w, p.w), dm1), 0.0f);
        {   // sorted insert: compares (old values) drive idx; med3 updates values
            bool c0=dd0<A0,c1=dd0<A1,c2=dd0<A2,c3=dd0<A3,c4=dd0<A4;
            IA4=c4?(c3?IA3:j):IA4; IA3=c3?(c2?IA2:j):IA3; IA2=c2?(c1?IA1:j):IA2;
            IA1=c1?(c0?IA0:j):IA1; IA0=c0?j:IA0;
            A4=__builtin_amdgcn_fmed3f(dd0,A3,A4); A3=__builtin_amdgcn_fmed3f(dd0,A2,A3);
            A2=__builtin_amdgcn_fmed3f(dd0,A1,A2); A1=__builtin_amdgcn_fmed3f(dd0,A0,A1);
            A0=fminf(A0,dd0);
        }
        {
            bool c0=dd1<B0,c1=dd1<B1,c2=dd1<B2,c3=dd1<B3,c4=dd1<B4;
            IB4=c4?(c3?IB3:j):IB4; IB3=c3?(c2?IB2:j):IB3; IB2=c2?(c1?IB1:j):IB2;
            IB1=c1?(c0?IB0:j):IB1; IB0=c0?j:IB0;
            B4=__builtin_amdgcn_fmed3f(dd1,B3,B4); B3=__builtin_amdgcn_fmed3f(dd1,B2,B3);
            B2=__builtin_amdgcn_fmed3f(dd1,B1,B2); B1=__builtin_amdgcn_fmed3f(dd1,B0,B1);
            B0=fminf(B0,dd1);
        }
    }

    float* wd = &dpart[sl * RSTR + pr * 10];
    unsigned short* wi = &ipart[sl * RSTR + pr * 10];
    wd[0]=A0; wd[1]=A1; wd[2]=A2; wd[3]=A3; wd[4]=A4;
    wd[5]=B0; wd[6]=B1; wd[7]=B2; wd[8]=B3; wd[9]=B4;
    wi[0]=(unsigned short)(IA0-j0); wi[1]=(unsigned short)(IA1-j0);
    wi[2]=(unsigned short)(IA2-j0); wi[3]=(unsigned short)(IA3-j0);
    wi[4]=(unsigned short)(IA4-j0);
    wi[5]=(unsigned short)(IB0-j0); wi[6]=(unsigned short)(IB1-j0);
    wi[7]=(unsigned short)(IB2-j0); wi[8]=(unsigned short)(IB3-j0);
    wi[9]=(unsigned short)(IB4-j0);
    __syncthreads();

    // ---------- merge: 64 threads (1 wave), 4 per row; short serial chains ----------
    if (t < 64) {
        int row = t >> 2, m = t & 3;             // row 0..15, sub-merger 0..3
        int pr2 = row >> 1, rs = row & 1;
        int gpr2 = pg * GPP + pr2;
        bool pact2 = gpr2 < total;
        int gp2 = pact2 ? gpr2 : (total - 1);
        int b2 = 0;
#pragma unroll
        for (int e = 1; e < BEV; e++) b2 += (gp2 >= sqp[e]) ? 1 : 0;
        int rp2 = gp2 - sqp[b2];
        int qc2 = sqc[b2], cc2 = scc[b2];
        int slen2 = (cc2 + NSL - 1) / NSL;
        int r = 2 * rp2 + rs;
        bool valid = pact2 && (r < qc2);

        unsigned long long a0=~0ull, a1u=~0ull, a2u=~0ull, a3u=~0ull, a4u=~0ull;
        for (int s2 = m; s2 < NSL; s2 += 4) {    // 8 slices per sub-merger
            const float* dp = &dpart[s2 * RSTR + pr2 * 10 + rs * 5];
            const unsigned short* ip = &ipart[s2 * RSTR + pr2 * 10 + rs * 5];
#pragma unroll
            for (int k = 0; k < KNN; k++) {
                unsigned long long key =
                    ((unsigned long long)__float_as_uint(dp[k]) << 32)
                    | (unsigned int)(s2 * slen2 + (int)ip[k]);
                INS5(key)                         // exact (d, pos) lex order
            }
        }
        // 2-step merge across the 4 sub-mergers (xor 1, 2 stays in 4-lane group);
        // unique keys => top-5-of-union independent of partition/order
#pragma unroll
        for (int off = 1; off <= 2; off <<= 1) {
            unsigned long long m0 = __shfl_xor(a0,  off, 64);
            unsigned long long m1 = __shfl_xor(a1u, off, 64);
            unsigned long long m2 = __shfl_xor(a2u, off, 64);
            unsigned long long m3 = __shfl_xor(a3u, off, 64);
            unsigned long long m4 = __shfl_xor(a4u, off, 64);
            INS5(m0) INS5(m1) INS5(m2) INS5(m3) INS5(m4)
        }

        if (valid && m == 0) {
            size_t eb2 = (size_t)b2 * S;
            int irow = qlist[eb2 + r];
            size_t gi = eb2 + irow;
            unsigned long long av[KNN] = {a0, a1u, a2u, a3u, a4u};
            float dk[KNN], nk[KNN], ev[KNN];
            float mx = -3.0e38f;
#pragma unroll
            for (int k = 0; k < KNN; k++) {
                float d = __uint_as_float((unsigned int)(av[k] >> 32));
                bool val = (d < BIGF);
                int cpos = (int)(unsigned int)(av[k] & 0xffffffffu);
                if (!val || cpos >= S || cpos < 0) cpos = 0;
                dk[k] = val ? d : 0.0f;
                nk[k] = val ? (float)(b2 * S + clist[eb2 + cpos]) : -1.0f;
                ev[k] = expf(-dk[k]);
                mx = fmaxf(mx, ev[k]);
            }
            float u[KNN], ssum = 0.0f;
#pragma unroll
            for (int k = 0; k < KNN; k++) { u[k] = expf(ev[k] - mx); ssum += u[k]; }
#pragma unroll
            for (int k = 0; k < KNN; k++) {
                out_nidx[gi * KNN + k] = nk[k];
                out_dist[gi * KNN + k] = dk[k];
                out_w[gi * KNN + k]    = u[k] / ssum;
            }
        }
    }
}

extern "C" void kernel_launch(void* const* d_in, const int* in_sizes, int n_in,
                              void* d_out, int out_size, void* d_ws, size_t ws_size,
                              hipStream_t stream) {
    const float* score  = (const float*)d_in[0];
    const float* coords = (const float*)d_in[1];

    float* out = (float*)d_out;
    size_t NK = (size_t)BEV * S * KNN;
    float* out_nidx = out;
    float* out_dist = out + NK;
    float* out_w    = out + 2 * NK;
    float* out_rsup = out + 3 * NK;
    float* out_sel  = out + 3 * NK + (BEV + 1);

    char* ws = (char*)d_ws;
    float* mrss4  = (float*)(ws + 0);                     // 64 f32
    int* qn       = (int*)(ws + 256);                     // 64
    int* cn       = (int*)(ws + 512);                     // 64
    int* qchoff   = (int*)(ws + 768);                     // 64
    int* cchoff   = (int*)(ws + 1024);                    // 64
    int* qcount   = (int*)(ws + 1280);                    // 16
    int* ccount   = (int*)(ws + 1344);                    // 16
    int* qpoff    = (int*)(ws + 1408);                    // 17
    int* scount   = (int*)(ws + 1536);                    // 64
    float* thrv   = (float*)(ws + 1792);                  // 1
    int* qlist    = (int*)(ws + 2048);                    // BEV*S
    int* clist    = (int*)(ws + 2048 + (size_t)BEV * S * 4);
    float4* qpts  = (float4*)(ws + 2048 + (size_t)BEV * S * 8);      // 16B aligned
    float4* ptsc  = (float4*)(ws + 2048 + (size_t)BEV * S * 8 + (size_t)BEV * S * 16);

    k_scan<<<BEV * 4, 1024, 0, stream>>>(score, mrss4, qn, cn);
    k_off<<<1, 64, 0, stream>>>(mrss4, qn, cn, thrv, qchoff, cchoff,
                                qcount, ccount, qpoff);
    k_sel<<<BEV * 4, 1024, 0, stream>>>(score, coords, thrv, qchoff, cchoff, scount,
                                        qlist, clist, qpts, ptsc,
                                        out_nidx, out_dist, out_w, out_sel);
    k_knn<<<(BEV * ((S + 1) / 2) + GPP - 1) / GPP, NTH, 0, stream>>>(
        ptsc, qpts, qlist, clist, qpoff, qcount, ccount, scount,
        out_nidx, out_dist, out_w, out_rsup);
}

// Round 23
// 82.837 us; speedup vs baseline: 1.3108x; 1.0184x over previous
//
#include <hip/hip_runtime.h>
#include <math.h>

#define S      4096
#define BEV    16
#define KNN    5
#define BIGF   1.0e9f
#define NSL    32           // slices per candidate scan
#define GPP    8            // query-pairs per knn block
#define NTH    256          // = GPP * NSL
#define RSTR   81           // per-slice LDS row stride in elements (GPP*10 + 1 pad)

__device__ __forceinline__ float fmulrn(float a, float b) { return __fmul_rn(a, b); }
__device__ __forceinline__ float faddrn(float a, float b) { return __fadd_rn(a, b); }

// thr from mrss4: MUST match bitwise across kernels (same op sequence)
__device__ __forceinline__ float thr_of(const float* __restrict__ mrss4) {
    float mn = 3.0e38f;
    for (int b = 0; b < BEV; b++) {
        float mx = mrss4[b * 4];
        for (int ch = 1; ch < 4; ch++) mx = fmaxf(mx, mrss4[b * 4 + ch]);
        mn = fminf(mn, mx);
    }
    return fminf(__fmul_rn(mn, 0.98f), 0.5f);   // rn(0.98x) monotone; clamp 0.5
}

// ---- K1: per-(event,chunk) stats: chunk max score, query/cand counts (no atomics) ----
__global__ __launch_bounds__(1024) void k_scan(const float* __restrict__ score,
                                               float* __restrict__ mrss4,
                                               int* __restrict__ qn, int* __restrict__ cn) {
    int blk = blockIdx.x, t = threadIdx.x;
    int b = blk >> 2, ch = blk & 3;
    float v = score[(size_t)b * S + ch * 1024 + t];
    float m = v;
    int pk = (v > 0.5f) ? (1 << 16) : 1;
#pragma unroll
    for (int off = 32; off >= 1; off >>= 1) {
        m = fmaxf(m, __shfl_xor(m, off, 64));
        pk += __shfl_xor(pk, off, 64);
    }
    __shared__ float wm[16];
    __shared__ int wp[16];
    int wid = t >> 6;
    if ((t & 63) == 0) { wm[wid] = m; wp[wid] = pk; }
    __syncthreads();
    if (t == 0) {
        float mm = wm[0]; int pp = wp[0];
        for (int w = 1; w < 16; w++) { mm = fmaxf(mm, wm[w]); pp += wp[w]; }
        mrss4[blk] = mm;
        qn[blk] = pp & 0xffff;
        cn[blk] = pp >> 16;
    }
}

// ---- K2: ordered compaction + sel_mask + candidate defaults + sel counts ----
// (thr + chunk offsets computed in-block from k_scan outputs; k_off eliminated)
__global__ __launch_bounds__(1024) void k_sel(const float* __restrict__ score,
                                              const float* __restrict__ coords,
                                              const float* __restrict__ mrss4,
                                              const int* __restrict__ qn,
                                              const int* __restrict__ cn,
                                              int* __restrict__ scount,
                                              int* __restrict__ qlist,
                                              int* __restrict__ clist,
                                              float4* __restrict__ qpts,
                                              float4* __restrict__ ptsc,
                                              float* __restrict__ out_nidx,
                                              float* __restrict__ out_dist,
                                              float* __restrict__ out_w,
                                              float* __restrict__ out_sel) {
    int blk = blockIdx.x, t = threadIdx.x;
    int b = blk >> 2, ch = blk & 3;
    float thr = thr_of(mrss4);
    int qcho = 0, ccho = 0;
    for (int c2 = 0; c2 < 4; c2++) {
        if (c2 < ch) { qcho += qn[b * 4 + c2]; ccho += cn[b * 4 + c2]; }
    }
    int p = ch * 1024 + t;
    size_t gi = (size_t)b * S + p;
    float v = score[gi];
    out_sel[gi] = (v >= thr) ? 1.0f : 0.0f;
    bool cand = (v > 0.5f);
    int pk = cand ? (1 << 16) : 1;
    int incl = pk;
#pragma unroll
    for (int off = 1; off < 64; off <<= 1) {
        int u = __shfl_up(incl, off, 64);
        if ((t & 63) >= off) incl += u;
    }
    __shared__ int wtot[16];
    __shared__ int wsel[16];
    int wid = t >> 6;
    if ((t & 63) == 63) wtot[wid] = incl;
    int sel = (v >= thr) ? 1 : 0;
#pragma unroll
    for (int off = 32; off >= 1; off >>= 1) sel += __shfl_xor(sel, off, 64);
    if ((t & 63) == 0) wsel[wid] = sel;
    __syncthreads();
    int base = 0;
    for (int w = 0; w < wid; w++) base += wtot[w];
    int excl = base + incl - pk;
    if (t == 0) {
        int sc2 = 0;
        for (int w = 0; w < 16; w++) sc2 += wsel[w];
        scount[blk] = sc2;
    }
    const float* c = coords + gi * 3;
    float x = c[0], y = c[1], z = c[2];
    float xx = faddrn(faddrn(fmulrn(x, x), fmulrn(y, y)), fmulrn(z, z));
    size_t ebase = (size_t)b * S;
    if (cand) {
        int pos = ccho + (excl >> 16);
        clist[ebase + pos] = p;
        ptsc[ebase + pos] = make_float4(fmulrn(-2.0f, x), fmulrn(-2.0f, y),
                                        fmulrn(-2.0f, z), xx);
        // direction-0 rows: fixed default outputs
#pragma unroll
        for (int k = 0; k < KNN; k++) {
            out_nidx[gi * KNN + k] = -1.0f;
            out_dist[gi * KNN + k] = 0.0f;
            out_w[gi * KNN + k]    = 0.2f;
        }
    } else {
        int pos = qcho + (excl & 0xffff);
        qlist[ebase + pos] = p;
        qpts[ebase + pos] = make_float4(x, y, z, xx);
    }
}

// strict-< sorted insert of one unique u64 key into the a0..a4u ladder
#define INS5(key) { \
    if ((key) < a4u) { \
        a4u = (key); \
        if (a4u < a3u) { unsigned long long u_ = a3u; a3u = a4u; a4u = u_; } \
        if (a3u < a2u) { unsigned long long u_ = a2u; a2u = a3u; a3u = u_; } \
        if (a2u < a1u) { unsigned long long u_ = a1u; a1u = a2u; a2u = u_; } \
        if (a1u < a0)  { unsigned long long u_ = a0;  a0  = a1u; a1u = u_; } \
    } }

// ---- K3: fused KNN: r10 scan (unroll 8) + 4-way split merge; offsets in-block ----
__global__ __launch_bounds__(NTH, 4) void k_knn(const float4* __restrict__ ptsc,
                                                const float4* __restrict__ qpts,
                                                const int* __restrict__ qlist,
                                                const int* __restrict__ clist,
                                                const int* __restrict__ qn,
                                                const int* __restrict__ cn,
                                                const int* __restrict__ scount,
                                                float* __restrict__ out_nidx,
                                                float* __restrict__ out_dist,
                                                float* __restrict__ out_w,
                                                float* __restrict__ out_rsup) {
    int pg = blockIdx.x, t = threadIdx.x;
    if (pg == 0 && t == 0) {                     // rs_up prefix (17 floats)
        int acc = 0;
        out_rsup[0] = 0.0f;
        for (int e = 0; e < BEV; e++) {
            acc += scount[e * 4] + scount[e * 4 + 1] + scount[e * 4 + 2] + scount[e * 4 + 3];
            out_rsup[e + 1] = (float)acc;
        }
    }

    __shared__ int sqp[BEV + 1];
    __shared__ int sqc[BEV];
    __shared__ int scc[BEV];
    __shared__ float dpart[NSL * RSTR];          // [sl][pr*10], 10368 B
    __shared__ unsigned short ipart[NSL * RSTR]; // 5184 B
    if (t < BEV) {
        sqc[t] = qn[t * 4] + qn[t * 4 + 1] + qn[t * 4 + 2] + qn[t * 4 + 3];
        scc[t] = cn[t * 4] + cn[t * 4 + 1] + cn[t * 4 + 2] + cn[t * 4 + 3];
    }
    __syncthreads();
    if (t == 0) {                                // 16-step prefix (pairs, same as k_off)
        int qp = 0;
        for (int e = 0; e < BEV; e++) { sqp[e] = qp; qp += (sqc[e] + 1) >> 1; }
        sqp[BEV] = qp;
    }
    __syncthreads();
    int total = sqp[BEV];
    if (pg * GPP >= total) return;               // uniform exit (after barriers: all waves)

    // ---------- scan phase (identical math to r10) ----------
    int pr = t & (GPP - 1), sl = t >> 3;         // 8 pairs x 32 slices
    int gpr = pg * GPP + pr;
    bool pact = gpr < total;
    int gp = pact ? gpr : (total - 1);
    int b = 0;
#pragma unroll
    for (int e = 1; e < BEV; e++) b += (gp >= sqp[e]) ? 1 : 0;
    int rp = gp - sqp[b];
    int qc = sqc[b], cc = scc[b];
    int r0 = 2 * rp, r1 = r0 + 1;
    bool a1v = pact && (r1 < qc);
    size_t ebase = (size_t)b * S;
    float4 q0 = qpts[ebase + r0];
    float4 q1 = qpts[ebase + (a1v ? r1 : r0)];

    int slen = (cc + NSL - 1) / NSL;
    int j0 = sl * slen;
    int j1 = min(j0 + slen, cc);

    const float INF = __int_as_float(0x7f800000);
    float A0=INF,A1=INF,A2=INF,A3=INF,A4=INF; int IA0=-1,IA1=-1,IA2=-1,IA3=-1,IA4=-1;
    float B0=INF,B1=INF,B2=INF,B3=INF,B4=INF; int IB0=-1,IB1=-1,IB2=-1,IB3=-1,IB4=-1;
    const float4* __restrict__ pp = ptsc + ebase;

#pragma unroll 8
    for (int j = j0; j < j1; j++) {
        float4 p = pp[j];                        // 8 distinct addrs per wave
        float dm0 = faddrn(faddrn(fmulrn(p.x, q0.x), fmulrn(p.y, q0.y)), fmulrn(p.z, q0.z));
        float dd0 = fmaxf(faddrn(faddrn(q0.w, p.w), dm0), 0.0f);
        float dm1 = faddrn(faddrn(fmulrn(p.x, q1.x), fmulrn(p.y, q1.y)), fmulrn(p.z, q1.z));
        float dd1 = fmaxf(faddrn(faddrn(q1.w, p.w), dm1), 0.0f);
        {   // sorted insert: compares (old values) drive idx; med3 updates values
            bool c0=dd0<A0,c1=dd0<A1,c2=dd0<A2,c3=dd0<A3,c4=dd0<A4;
            IA4=c4?(c3?IA3:j):IA4; IA3=c3?(c2?IA2:j):IA3; IA2=c2?(c1?IA1:j):IA2;
            IA1=c1?(c0?IA0:j):IA1; IA0=c0?j:IA0;
            A4=__builtin_amdgcn_fmed3f(dd0,A3,A4); A3=__builtin_amdgcn_fmed3f(dd0,A2,A3);
            A2=__builtin_amdgcn_fmed3f(dd0,A1,A2); A1=__builtin_amdgcn_fmed3f(dd0,A0,A1);
            A0=fminf(A0,dd0);
        }
        {
            bool c0=dd1<B0,c1=dd1<B1,c2=dd1<B2,c3=dd1<B3,c4=dd1<B4;
            IB4=c4?(c3?IB3:j):IB4; IB3=c3?(c2?IB2:j):IB3; IB2=c2?(c1?IB1:j):IB2;
            IB1=c1?(c0?IB0:j):IB1; IB0=c0?j:IB0;
            B4=__builtin_amdgcn_fmed3f(dd1,B3,B4); B3=__builtin_amdgcn_fmed3f(dd1,B2,B3);
            B2=__builtin_amdgcn_fmed3f(dd1,B1,B2); B1=__builtin_amdgcn_fmed3f(dd1,B0,B1);
            B0=fminf(B0,dd1);
        }
    }

    float* wd = &dpart[sl * RSTR + pr * 10];
    unsigned short* wi = &ipart[sl * RSTR + pr * 10];
    wd[0]=A0; wd[1]=A1; wd[2]=A2; wd[3]=A3; wd[4]=A4;
    wd[5]=B0; wd[6]=B1; wd[7]=B2; wd[8]=B3; wd[9]=B4;
    wi[0]=(unsigned short)(IA0-j0); wi[1]=(unsigned short)(IA1-j0);
    wi[2]=(unsigned short)(IA2-j0); wi[3]=(unsigned short)(IA3-j0);
    wi[4]=(unsigned short)(IA4-j0);
    wi[5]=(unsigned short)(IB0-j0); wi[6]=(unsigned short)(IB1-j0);
    wi[7]=(unsigned short)(IB2-j0); wi[8]=(unsigned short)(IB3-j0);
    wi[9]=(unsigned short)(IB4-j0);
    __syncthreads();

    // ---------- merge: 64 threads (1 wave), 4 per row; short serial chains ----------
    if (t < 64) {
        int row = t >> 2, m = t & 3;             // row 0..15, sub-merger 0..3
        int pr2 = row >> 1, rs = row & 1;
        int gpr2 = pg * GPP + pr2;
        bool pact2 = gpr2 < total;
        int gp2 = pact2 ? gpr2 : (total - 1);
        int b2 = 0;
#pragma unroll
        for (int e = 1; e < BEV; e++) b2 += (gp2 >= sqp[e]) ? 1 : 0;
        int rp2 = gp2 - sqp[b2];
        int qc2 = sqc[b2], cc2 = scc[b2];
        int slen2 = (cc2 + NSL - 1) / NSL;
        int r = 2 * rp2 + rs;
        bool valid = pact2 && (r < qc2);

        unsigned long long a0=~0ull, a1u=~0ull, a2u=~0ull, a3u=~0ull, a4u=~0ull;
        for (int s2 = m; s2 < NSL; s2 += 4) {    // 8 slices per sub-merger
            const float* dp = &dpart[s2 * RSTR + pr2 * 10 + rs * 5];
            const unsigned short* ip = &ipart[s2 * RSTR + pr2 * 10 + rs * 5];
#pragma unroll
            for (int k = 0; k < KNN; k++) {
                unsigned long long key =
                    ((unsigned long long)__float_as_uint(dp[k]) << 32)
                    | (unsigned int)(s2 * slen2 + (int)ip[k]);
                INS5(key)                         // exact (d, pos) lex order
            }
        }
        // 2-step merge across the 4 sub-mergers; unique keys => order-independent
#pragma unroll
        for (int off = 1; off <= 2; off <<= 1) {
            unsigned long long m0 = __shfl_xor(a0,  off, 64);
            unsigned long long m1 = __shfl_xor(a1u, off, 64);
            unsigned long long m2 = __shfl_xor(a2u, off, 64);
            unsigned long long m3 = __shfl_xor(a3u, off, 64);
            unsigned long long m4 = __shfl_xor(a4u, off, 64);
            INS5(m0) INS5(m1) INS5(m2) INS5(m3) INS5(m4)
        }

        if (valid && m == 0) {
            size_t eb2 = (size_t)b2 * S;
            int irow = qlist[eb2 + r];
            size_t gi = eb2 + irow;
            unsigned long long av[KNN] = {a0, a1u, a2u, a3u, a4u};
            float dk[KNN], nk[KNN], ev[KNN];
            float mx = -3.0e38f;
#pragma unroll
            for (int k = 0; k < KNN; k++) {
                float d = __uint_as_float((unsigned int)(av[k] >> 32));
                bool val = (d < BIGF);
                int cpos = (int)(unsigned int)(av[k] & 0xffffffffu);
                if (!val || cpos >= S || cpos < 0) cpos = 0;
                dk[k] = val ? d : 0.0f;
                nk[k] = val ? (float)(b2 * S + clist[eb2 + cpos]) : -1.0f;
                ev[k] = expf(-dk[k]);
                mx = fmaxf(mx, ev[k]);
            }
            float u[KNN], ssum = 0.0f;
#pragma unroll
            for (int k = 0; k < KNN; k++) { u[k] = expf(ev[k] - mx); ssum += u[k]; }
#pragma unroll
            for (int k = 0; k < KNN; k++) {
                out_nidx[gi * KNN + k] = nk[k];
                out_dist[gi * KNN + k] = dk[k];
                out_w[gi * KNN + k]    = u[k] / ssum;
            }
        }
    }
}

extern "C" void kernel_launch(void* const* d_in, const int* in_sizes, int n_in,
                              void* d_out, int out_size, void* d_ws, size_t ws_size,
                              hipStream_t stream) {
    const float* score  = (const float*)d_in[0];
    const float* coords = (const float*)d_in[1];

    float* out = (float*)d_out;
    size_t NK = (size_t)BEV * S * KNN;
    float* out_nidx = out;
    float* out_dist = out + NK;
    float* out_w    = out + 2 * NK;
    float* out_rsup = out + 3 * NK;
    float* out_sel  = out + 3 * NK + (BEV + 1);

    char* ws = (char*)d_ws;
    float* mrss4  = (float*)(ws + 0);                     // 64 f32
    int* qn       = (int*)(ws + 256);                     // 64
    int* cn       = (int*)(ws + 512);                     // 64
    int* scount   = (int*)(ws + 1536);                    // 64
    int* qlist    = (int*)(ws + 2048);                    // BEV*S
    int* clist    = (int*)(ws + 2048 + (size_t)BEV * S * 4);
    float4* qpts  = (float4*)(ws + 2048 + (size_t)BEV * S * 8);      // 16B aligned
    float4* ptsc  = (float4*)(ws + 2048 + (size_t)BEV * S * 8 + (size_t)BEV * S * 16);

    k_scan<<<BEV * 4, 1024, 0, stream>>>(score, mrss4, qn, cn);
    k_sel<<<BEV * 4, 1024, 0, stream>>>(score, coords, mrss4, qn, cn, scount,
                                        qlist, clist, qpts, ptsc,
                                        out_nidx, out_dist, out_w, out_sel);
    k_knn<<<(BEV * ((S + 1) / 2) + GPP - 1) / GPP, NTH, 0, stream>>>(
        ptsc, qpts, qlist, clist, qn, cn, scount,
        out_nidx, out_dist, out_w, out_rsup);
}